// Round 14
// baseline (170.234 us; speedup 1.0000x reference)
//
#include <hip/hip_runtime.h>
#include <hip/hip_bf16.h>

#define B_ROWS 131072
#define H 128
#define TILES 8
#define NBLK 512

typedef __bf16 bf16x8 __attribute__((ext_vector_type(8)));
typedef float f32x4 __attribute__((ext_vector_type(4)));

#define LOG2E 1.4426950408889634f

__device__ __forceinline__ float fast_sigmoid(float v) {
    return __builtin_amdgcn_rcpf(1.0f + __builtin_amdgcn_exp2f(-LOG2E * v));
}
__device__ __forceinline__ float fast_tanh(float v) {
    return 1.0f - 2.0f * __builtin_amdgcn_rcpf(1.0f + __builtin_amdgcn_exp2f(2.0f * LOG2E * v));
}

struct WPtrs {
    const float* wx[4];
    const float* wh[4];
    const float* bx[4];
    const float* bh[4];
};

// Wcat[n][k]: n = gate*128 + unit, k in [0,256) = [X-k | h-k]. bsum[n] = bx+bh.
__global__ __launch_bounds__(256) void prep_weights(WPtrs p, __bf16* __restrict__ wcat,
                                                    float* __restrict__ bsum) {
    int n = blockIdx.x;
    int k = threadIdx.x;
    int g = n >> 7, r = n & 127;
    float v = (k < H) ? p.wx[g][r * H + k] : p.wh[g][r * H + (k - H)];
    wcat[n * 256 + k] = (__bf16)v;
    if (k == 0) bsum[n] = p.bx[g][r] + p.bh[g][r];
}

// R14: NO LDS, NO barriers. R13 showed weights pin to AGPRs (clean traffic,
// arch-VGPR 116) but lockstep slab cadence kept dur ~90us. Here each wave
// free-runs: 32 rows x 16 units x 4 gates, A-fragments straight from global
// (16 rows x 128B contiguous per wave-access = full lines, L1-shared across
// the block's 8 waves), 2-deep kc prefetch, per-wave exact vmcnt waits.
__global__ __launch_bounds__(512, 1) void lstm_fused(
    const float* __restrict__ X, const float* __restrict__ Hp, const float* __restrict__ Cp,
    const __bf16* __restrict__ Wcat, const float* __restrict__ Bsum,
    float* __restrict__ out)
{
    const int t = threadIdx.x;
    const int lane = t & 63;
    const int wv = t >> 6;                  // 0..7: unit group
    const int l16 = lane & 15;
    const int kg = lane >> 4;               // 0..3
    const long strip = (long)blockIdx.x * (32 * TILES);
    const long c_off = (long)B_ROWS * H;
    const int j = wv * 16 + l16;            // this lane's unit (all 4 gates)

    // ---- B -> registers once (L2-resident Wcat), pinned via asm outputs (-> AGPRs) ----
    bf16x8 wreg[4][8];
    {
        const __bf16* wb = Wcat + (long)j * 256 + kg * 8;
#pragma unroll
        for (int g = 0; g < 4; ++g)
#pragma unroll
            for (int kc = 0; kc < 8; ++kc) {
                wreg[g][kc] = *(const bf16x8*)(wb + g * (128 * 256) + kc * 32);
                asm volatile("" : "+v"(wreg[g][kc]));
            }
    }
    float bias[4];
#pragma unroll
    for (int g = 0; g < 4; ++g) bias[g] = Bsum[g * H + j];

    auto loadA = [&](float4* A, long r0, int kc) {
        const float* src = (kc < 4) ? X : Hp;
        const int col = (kc & 3) * 32 + kg * 8;
#pragma unroll
        for (int rt = 0; rt < 2; ++rt) {
            const float* p = src + (r0 + rt * 16 + l16) * (long)H + col;
            A[rt * 2]     = *(const float4*)p;
            A[rt * 2 + 1] = *(const float4*)(p + 4);
        }
    };
    auto cvt = [&](const float4* A, bf16x8* a) {
#pragma unroll
        for (int rt = 0; rt < 2; ++rt) {
            union { __bf16 e[8]; bf16x8 v; } u;
            float4 lo = A[rt * 2], hi = A[rt * 2 + 1];
            u.e[0] = (__bf16)lo.x; u.e[1] = (__bf16)lo.y;
            u.e[2] = (__bf16)lo.z; u.e[3] = (__bf16)lo.w;
            u.e[4] = (__bf16)hi.x; u.e[5] = (__bf16)hi.y;
            u.e[6] = (__bf16)hi.z; u.e[7] = (__bf16)hi.w;
            a[rt] = u.v;
        }
    };

    for (int tile = 0; tile < TILES; ++tile) {
        const long r0 = strip + tile * 32;

        // cp loads first (oldest in FIFO -> never waited on until epilogue)
        float cpv[8];
#pragma unroll
        for (int rt = 0; rt < 2; ++rt)
#pragma unroll
            for (int r = 0; r < 4; ++r)
                cpv[rt * 4 + r] = Cp[(r0 + rt * 16 + kg * 4 + r) * (long)H + j];

        float4 A0[4], A1[4];
        loadA(A0, r0, 0);
        loadA(A1, r0, 1);

        f32x4 acc[4][2] = {};
#pragma unroll
        for (int kc = 0; kc < 8; ++kc) {
            float4* cur = (kc & 1) ? A1 : A0;
            bf16x8 a[2];
            cvt(cur, a);                    // waits (exact vmcnt) for cur only
            if (kc < 6) loadA(cur, r0, kc + 2);   // reuse regs: 2-deep prefetch
#pragma unroll
            for (int g = 0; g < 4; ++g) {
                acc[g][0] = __builtin_amdgcn_mfma_f32_16x16x32_bf16(a[0], wreg[g][kc], acc[g][0], 0, 0, 0);
                acc[g][1] = __builtin_amdgcn_mfma_f32_16x16x32_bf16(a[1], wreg[g][kc], acc[g][1], 0, 0, 0);
            }
        }

        // epilogue: gates lane-local (C/D row=(lane>>4)*4+reg, col=lane&15)
#pragma unroll
        for (int rt = 0; rt < 2; ++rt) {
#pragma unroll
            for (int r = 0; r < 4; ++r) {
                long row = r0 + rt * 16 + kg * 4 + r;
                float fg = acc[0][rt][r] + bias[0];
                float ig = acc[1][rt][r] + bias[1];
                float cg = acc[2][rt][r] + bias[2];
                float og = acc[3][rt][r] + bias[3];
                float ft = fast_sigmoid(fg);
                float it = fast_sigmoid(ig);
                float cc = fast_tanh(cg);
                float ot = fast_sigmoid(og);
                float ct = ft * cpv[rt * 4 + r] + it * cc;
                float ht = ot * fast_tanh(ct);
                out[row * H + j] = ht;
                out[c_off + row * H + j] = ct;
            }
        }
    }
}

extern "C" void kernel_launch(void* const* d_in, const int* in_sizes, int n_in,
                              void* d_out, int out_size, void* d_ws, size_t ws_size,
                              hipStream_t stream) {
    const float* X  = (const float*)d_in[0];
    const float* Hp = (const float*)d_in[1];
    const float* Cp = (const float*)d_in[2];
    WPtrs p;
    p.wx[0] = (const float*)d_in[3];  p.bx[0] = (const float*)d_in[4];
    p.wh[0] = (const float*)d_in[5];  p.bh[0] = (const float*)d_in[6];
    p.wx[1] = (const float*)d_in[7];  p.bx[1] = (const float*)d_in[8];
    p.wh[1] = (const float*)d_in[9];  p.bh[1] = (const float*)d_in[10];
    p.wx[2] = (const float*)d_in[11]; p.bx[2] = (const float*)d_in[12];
    p.wh[2] = (const float*)d_in[13]; p.bh[2] = (const float*)d_in[14];
    p.wx[3] = (const float*)d_in[15]; p.bx[3] = (const float*)d_in[16];
    p.wh[3] = (const float*)d_in[17]; p.bh[3] = (const float*)d_in[18];

    __bf16* wcat = (__bf16*)d_ws;
    float*  bsum = (float*)((char*)d_ws + 512 * 256 * 2);

    prep_weights<<<512, 256, 0, stream>>>(p, wcat, bsum);
    lstm_fused<<<NBLK, 512, 0, stream>>>(X, Hp, Cp, wcat, bsum, (float*)d_out);
}